// Round 1
// baseline (896.708 us; speedup 1.0000x reference)
//
#include <hip/hip_runtime.h>

typedef unsigned short u16;
typedef u16 u16x8 __attribute__((ext_vector_type(8)));
typedef __bf16 bf16x8 __attribute__((ext_vector_type(8)));
typedef float f32x4 __attribute__((ext_vector_type(4)));

__device__ __forceinline__ float b2f(u16 u) {
    union { unsigned int i; float f; } v; v.i = ((unsigned int)u) << 16; return v.f;
}
__device__ __forceinline__ u16 f2b(float f) {
    union { float f; unsigned int i; } v; v.f = f;
    unsigned int r = v.i + 0x7fffu + ((v.i >> 16) & 1u);
    return (u16)(r >> 16);
}

// ---------------------------------------------------------------------------
// Pack weights to bf16. wcat = [wq1*scale ; wkv_k*scale ; wkv_v] (2304x768).
// wq2T = wq2 transposed (k-major) for the small agent-token GEMM. wpb = wproj.
// scale = hd^-0.5 = 0.125 folded into q and k.
// ---------------------------------------------------------------------------
__global__ __launch_bounds__(256) void pack_w_kernel(
    const float* __restrict__ wq1, const float* __restrict__ wq2,
    const float* __restrict__ wkv, const float* __restrict__ wproj,
    u16* __restrict__ wcat, u16* __restrict__ wq2T, u16* __restrict__ wpb) {
    int e = blockIdx.x * 256 + threadIdx.x;   // grid covers exactly 768*768
    const float scale = 0.125f;
    int o = e / 768, c = e - o * 768;
    wcat[e]           = f2b(wq1[e] * scale);
    wcat[589824 + e]  = f2b(wkv[e] * scale);
    wcat[1179648 + e] = f2b(wkv[589824 + e]);
    wq2T[c * 768 + o] = f2b(wq2[e]);
    wpb[e]            = f2b(wproj[e]);
}

// ---------------------------------------------------------------------------
// LN over channel dim of x (b,c,h*w) -> xn (b, n, c) bf16, LDS-transposed.
// Block: 64 positions x 768 channels, 256 threads.
// ---------------------------------------------------------------------------
__global__ __launch_bounds__(256) void ln_x_kernel(
    const float* __restrict__ x, const float* __restrict__ lw,
    const float* __restrict__ lb, u16* __restrict__ xn) {
    __shared__ float red[8][64];
    __shared__ float smu[64];
    __shared__ float srs[64];
    __shared__ float tl[64][65];
    const int bx = blockIdx.x;
    const int b = bx / 49, tile = bx - b * 49;
    const int pos0 = tile * 64;
    const int t = threadIdx.x;
    const int p = t & 63, q = t >> 6;
    const float* xb = x + (size_t)b * 2408448 + pos0;
    float s = 0.f, s2 = 0.f;
    for (int c = q; c < 768; c += 4) {
        float v = xb[(size_t)c * 3136 + p];
        s += v; s2 += v * v;
    }
    red[q][p] = s; red[4 + q][p] = s2;
    __syncthreads();
    if (t < 64) {
        float ss = red[0][t] + red[1][t] + red[2][t] + red[3][t];
        float qq = red[4][t] + red[5][t] + red[6][t] + red[7][t];
        float mu = ss * (1.0f / 768.0f);
        float var = qq * (1.0f / 768.0f) - mu * mu;
        smu[t] = mu;
        srs[t] = rsqrtf(var + 1e-5f);
    }
    __syncthreads();
    const size_t orow0 = ((size_t)b * 3136 + pos0) * 768;
    for (int ctile = 0; ctile < 12; ++ctile) {
        const int c0 = ctile * 64;
        #pragma unroll
        for (int ii = 0; ii < 16; ++ii) {
            int ci = q + ii * 4;
            tl[ci][p] = xb[(size_t)(c0 + ci) * 3136 + p];
        }
        __syncthreads();
        const float wv = lw[c0 + p], bv = lb[c0 + p];
        #pragma unroll
        for (int ii = 0; ii < 16; ++ii) {
            int pi = q + ii * 4;
            float v = tl[p][pi];
            float nv = (v - smu[pi]) * srs[pi] * wv + bv;
            xn[orow0 + (size_t)pi * 768 + (c0 + p)] = f2b(nv);
        }
        __syncthreads();
    }
}

// ---------------------------------------------------------------------------
// LN over channels of y + 8x8 spatial mean-pool -> ypool (b, 49, 768) f32.
// Pooling commutes with the later linear projection, so we pool FIRST.
// Block per (b, agent). 64 positions.
// ---------------------------------------------------------------------------
__global__ __launch_bounds__(256) void ln_y_pool_kernel(
    const float* __restrict__ y, const float* __restrict__ lw,
    const float* __restrict__ lb, float* __restrict__ ypool) {
    __shared__ float red[8][64];
    __shared__ float smu[64];
    __shared__ float srs[64];
    const int bx = blockIdx.x;
    const int b = bx / 49, a = bx - b * 49;
    const int pi_ = a / 7, pj = a - pi_ * 7;
    const int t = threadIdx.x, p = t & 63, q = t >> 6;
    const int hi = pi_ * 8 + (p >> 3), wi = pj * 8 + (p & 7);
    const int pos = hi * 56 + wi;
    const float* yb = y + (size_t)b * 2408448;
    float s = 0.f, s2 = 0.f;
    for (int c = q; c < 768; c += 4) {
        float v = yb[(size_t)c * 3136 + pos];
        s += v; s2 += v * v;
    }
    red[q][p] = s; red[4 + q][p] = s2;
    __syncthreads();
    if (t < 64) {
        float ss = red[0][t] + red[1][t] + red[2][t] + red[3][t];
        float qq = red[4][t] + red[5][t] + red[6][t] + red[7][t];
        float mu = ss * (1.0f / 768.0f);
        float var = qq * (1.0f / 768.0f) - mu * mu;
        smu[t] = mu;
        srs[t] = rsqrtf(var + 1e-5f);
    }
    __syncthreads();
    const float mu = smu[p], rs = srs[p];
    float* yout = ypool + ((size_t)b * 49 + a) * 768;
    for (int c = q; c < 768; c += 4) {
        float v = yb[(size_t)c * 3136 + pos];
        float nv = (v - mu) * rs * lw[c] + lb[c];
        #pragma unroll
        for (int m = 1; m < 64; m <<= 1) nv += __shfl_xor(nv, m, 64);
        if (p == 0) yout[c] = nv * (1.0f / 64.0f);
    }
}

// ---------------------------------------------------------------------------
// bf16 MFMA GEMM, C = A(MxK) * B(NxK)^T. K=768. 128x128 tile, BK=64, 4 waves
// (2x2), per-wave 64x64 via 4x4 fragments of 16x16x32. Reg-staged LDS with
// XOR slot swizzle (slot ^= row&7) to avoid 16-way ds_read_b128 conflicts.
// PROJ=false: C -> bf16 row-major (ldc = N).
// PROJ=true : C -> f32, +bias, written TRANSPOSED to (b, o, n) layout.
// ---------------------------------------------------------------------------
template<bool PROJ>
__global__ __launch_bounds__(256) void gemm_bt_kernel(
    const u16* __restrict__ A, const u16* __restrict__ B,
    u16* __restrict__ Cb, float* __restrict__ Cf,
    const float* __restrict__ bias, int N) {
    __shared__ u16 As[128 * 64];
    __shared__ u16 Bs[128 * 64];
    const int t = threadIdx.x;
    const int lane = t & 63;
    const int w = t >> 6;
    const int wr = w >> 1, wc = w & 1;
    const int ct = blockIdx.x, rt = blockIdx.y;
    const int srow = t >> 3;
    const int scol = (t & 7) * 8;
    const int sslot = t & 7;
    const u16* Ab = A + (size_t)rt * 128 * 768;
    const u16* Bb = B + (size_t)ct * 128 * 768;

    f32x4 acc[4][4];
    #pragma unroll
    for (int mi = 0; mi < 4; ++mi)
        #pragma unroll
        for (int ni = 0; ni < 4; ++ni)
            acc[mi][ni] = (f32x4){0.f, 0.f, 0.f, 0.f};

    u16x8 avr[4], bvr[4];
    #pragma unroll
    for (int i = 0; i < 4; ++i) {
        int row = srow + i * 32;
        avr[i] = *(const u16x8*)(Ab + (size_t)row * 768 + scol);
        bvr[i] = *(const u16x8*)(Bb + (size_t)row * 768 + scol);
    }

    for (int kt = 0; kt < 12; ++kt) {
        __syncthreads();
        #pragma unroll
        for (int i = 0; i < 4; ++i) {
            int row = srow + i * 32;
            int sl = sslot ^ (row & 7);
            *(u16x8*)&As[row * 64 + sl * 8] = avr[i];
            *(u16x8*)&Bs[row * 64 + sl * 8] = bvr[i];
        }
        __syncthreads();
        if (kt < 11) {
            #pragma unroll
            for (int i = 0; i < 4; ++i) {
                int row = srow + i * 32;
                avr[i] = *(const u16x8*)(Ab + (size_t)row * 768 + (kt + 1) * 64 + scol);
                bvr[i] = *(const u16x8*)(Bb + (size_t)row * 768 + (kt + 1) * 64 + scol);
            }
        }
        #pragma unroll
        for (int ks = 0; ks < 2; ++ks) {
            bf16x8 af[4], bfv[4];
            #pragma unroll
            for (int mi = 0; mi < 4; ++mi) {
                int row = wr * 64 + mi * 16 + (lane & 15);
                int slot = ks * 4 + (lane >> 4);
                af[mi] = *(const bf16x8*)&As[row * 64 + ((slot ^ (row & 7)) * 8)];
            }
            #pragma unroll
            for (int ni = 0; ni < 4; ++ni) {
                int row = wc * 64 + ni * 16 + (lane & 15);
                int slot = ks * 4 + (lane >> 4);
                bfv[ni] = *(const bf16x8*)&Bs[row * 64 + ((slot ^ (row & 7)) * 8)];
            }
            #pragma unroll
            for (int mi = 0; mi < 4; ++mi)
                #pragma unroll
                for (int ni = 0; ni < 4; ++ni)
                    acc[mi][ni] = __builtin_amdgcn_mfma_f32_16x16x32_bf16(
                        af[mi], bfv[ni], acc[mi][ni], 0, 0, 0);
        }
    }

    if constexpr (!PROJ) {
        #pragma unroll
        for (int mi = 0; mi < 4; ++mi)
            #pragma unroll
            for (int ni = 0; ni < 4; ++ni) {
                int row0 = rt * 128 + wr * 64 + mi * 16 + (lane >> 4) * 4;
                int col = ct * 128 + wc * 64 + ni * 16 + (lane & 15);
                #pragma unroll
                for (int r = 0; r < 4; ++r)
                    Cb[(size_t)(row0 + r) * N + col] = f2b(acc[mi][ni][r]);
            }
    } else {
        #pragma unroll
        for (int ni = 0; ni < 4; ++ni) {
            int col = ct * 128 + wc * 64 + ni * 16 + (lane & 15);   // output channel o
            float bv = bias[col];
            #pragma unroll
            for (int mi = 0; mi < 4; ++mi) {
                int grow = rt * 128 + wr * 64 + mi * 16 + (lane >> 4) * 4; // 4 consec n
                int bb = grow / 3136;
                int nn = grow - bb * 3136;
                f32x4 vv = acc[mi][ni];
                vv[0] += bv; vv[1] += bv; vv[2] += bv; vv[3] += bv;
                *(f32x4*)(Cf + (size_t)bb * 2408448 + (size_t)col * 3136 + nn) = vv;
            }
        }
    }
}

// ---------------------------------------------------------------------------
// agent_tokens = ypool @ wq2T : (8*49) x 768, K=768. Small GEMM, f32 out.
// Block per (b, agent-group of 7, n-tile of 256).
// ---------------------------------------------------------------------------
__global__ __launch_bounds__(256) void at_gemm_kernel(
    const float* __restrict__ ypool, const u16* __restrict__ wq2T,
    float* __restrict__ at) {
    __shared__ float y7[7][768];
    const int bx = blockIdx.x;     // b*21 + ag*3 + nt
    const int b = bx / 21, rem = bx - b * 21;
    const int ag = rem / 3, nt = rem - ag * 3;
    const int t = threadIdx.x;
    const int abase = ag * 7;
    const float* ysrc = ypool + ((size_t)b * 49 + abase) * 768;
    for (int e = t; e < 7 * 768; e += 256) y7[e / 768][e % 768] = ysrc[e];
    __syncthreads();
    const int n = nt * 256 + t;
    float acc[7];
    #pragma unroll
    for (int j = 0; j < 7; ++j) acc[j] = 0.f;
    for (int k = 0; k < 768; ++k) {
        float wv = b2f(wq2T[(size_t)k * 768 + n]);
        #pragma unroll
        for (int j = 0; j < 7; ++j) acc[j] += y7[j][k] * wv;
    }
    #pragma unroll
    for (int j = 0; j < 7; ++j)
        at[((size_t)b * 49 + abase + j) * 768 + n] = acc[j];
}

// ---------------------------------------------------------------------------
// Agent-side attention, n-split into 7 partials per (b,h).
// logits = at_head (49x64) . k^T (64-tile), P = exp (logits tiny, max-free),
// partial sums sA[49] + partial PV accumulation (regs, lane = v-dim).
// ---------------------------------------------------------------------------
__global__ __launch_bounds__(256) void agent_attn_kernel(
    const float* __restrict__ at, const u16* __restrict__ qkv,
    float* __restrict__ ps, float* __restrict__ pav) {
    __shared__ float atile[49 * 64];
    __shared__ float ktile[64 * 64];   // slot-swizzled rows
    __shared__ float vtile[64 * 64];   // slot-swizzled rows
    __shared__ float P[49 * 64];       // P[a][i]
    __shared__ float sA[49];
    const int ns = blockIdx.x;         // 0..6
    const int bh = blockIdx.y;         // 0..95
    const int b = bh / 12, h = bh - b * 12;
    const int t = threadIdx.x, lane = t & 63, w = t >> 6;
    const float* atsrc = at + (size_t)b * 49 * 768 + h * 64;
    for (int e = t; e < 49 * 64; e += 256)
        atile[e] = atsrc[(size_t)(e >> 6) * 768 + (e & 63)];
    if (t < 49) sA[t] = 0.f;
    float accv[13];
    #pragma unroll
    for (int i = 0; i < 13; ++i) accv[i] = 0.f;
    const int si = t >> 2, sseg = t & 3;

    for (int tile = 0; tile < 7; ++tile) {
        const int n0 = ns * 448 + tile * 64;
        {   // stage k,v (16 bf16 each per thread), swizzled f32x4 slots
            const u16* kp = qkv + ((size_t)(b * 3136 + n0 + si)) * 2304 + 768 + h * 64 + sseg * 16;
            u16x8 k0 = *(const u16x8*)kp, k1 = *(const u16x8*)(kp + 8);
            u16x8 v0 = *(const u16x8*)(kp + 768), v1 = *(const u16x8*)(kp + 776);
            #pragma unroll
            for (int half = 0; half < 2; ++half) {
                u16x8 kk = half ? k1 : k0;
                u16x8 vv = half ? v1 : v0;
                #pragma unroll
                for (int q2 = 0; q2 < 2; ++q2) {
                    int sl = sseg * 4 + half * 2 + q2;
                    int col = ((sl ^ (si & 7)) << 2);
                    f32x4 kf = { b2f(kk[q2*4+0]), b2f(kk[q2*4+1]), b2f(kk[q2*4+2]), b2f(kk[q2*4+3]) };
                    f32x4 vf = { b2f(vv[q2*4+0]), b2f(vv[q2*4+1]), b2f(vv[q2*4+2]), b2f(vv[q2*4+3]) };
                    *(f32x4*)&ktile[si * 64 + col] = kf;
                    *(f32x4*)&vtile[si * 64 + col] = vf;
                }
            }
        }
        __syncthreads();
        // logits + exp + running sum; wave w owns agents a = w + 4k; lane = position i
        #pragma unroll
        for (int idx = 0; idx < 13; ++idx) {
            int a = w + idx * 4;
            if (a < 49) {
                f32x4 acc4 = {0.f, 0.f, 0.f, 0.f};
                #pragma unroll
                for (int sl = 0; sl < 16; ++sl) {
                    f32x4 at4 = *(const f32x4*)&atile[a * 64 + sl * 4];
                    f32x4 k4 = *(const f32x4*)&ktile[lane * 64 + ((sl ^ (lane & 7)) << 2)];
                    acc4 += at4 * k4;
                }
                float pexp = __expf(acc4[0] + acc4[1] + acc4[2] + acc4[3]);
                P[a * 64 + lane] = pexp;
                float rs_ = pexp;
                #pragma unroll
                for (int m = 1; m < 64; m <<= 1) rs_ += __shfl_xor(rs_, m, 64);
                if (lane == 0) sA[a] += rs_;
            }
        }
        __syncthreads();
        // PV: lane = v-dim j; accv[idx] += sum_i P[a][i] * v[i][j]
        #pragma unroll
        for (int i0 = 0; i0 < 64; i0 += 4) {
            float vr[4];
            #pragma unroll
            for (int ii = 0; ii < 4; ++ii) {
                int row = i0 + ii;
                vr[ii] = vtile[row * 64 + ((((lane >> 2) ^ (row & 7)) << 2) | (lane & 3))];
            }
            #pragma unroll
            for (int idx = 0; idx < 13; ++idx) {
                int a = w + idx * 4;
                if (a < 49) {
                    f32x4 p4 = *(const f32x4*)&P[a * 64 + i0];
                    accv[idx] += p4[0]*vr[0] + p4[1]*vr[1] + p4[2]*vr[2] + p4[3]*vr[3];
                }
            }
        }
        __syncthreads();
    }
    const size_t pbase = ((size_t)bh * 7 + ns) * 49;
    if (t < 49) ps[pbase + t] = sA[t];
    #pragma unroll
    for (int idx = 0; idx < 13; ++idx) {
        int a = w + idx * 4;
        if (a < 49) pav[(pbase + a) * 64 + lane] = accv[idx];
    }
}

__global__ __launch_bounds__(256) void combine_kernel(
    const float* __restrict__ ps, const float* __restrict__ pav,
    float* __restrict__ agent_v) {
    const int bh = blockIdx.x;
    const int t = threadIdx.x, lane = t & 63, w = t >> 6;
    for (int a = w; a < 49; a += 4) {
        float s = 0.f, vsum = 0.f;
        #pragma unroll
        for (int ns = 0; ns < 7; ++ns) {
            size_t pb = ((size_t)bh * 7 + ns) * 49 + a;
            s += ps[pb];
            vsum += pav[pb * 64 + lane];
        }
        agent_v[((size_t)bh * 49 + a) * 64 + lane] = vsum / s;
    }
}

// ---------------------------------------------------------------------------
// Q-side attention per (b,h, 64-position tile): softmax over 49 agents of
// q.at^T, then out = P @ agent_v, written bf16 to attn_out (b,n,c).
// ---------------------------------------------------------------------------
__global__ __launch_bounds__(256) void q_attn_kernel(
    const float* __restrict__ at, const u16* __restrict__ qkv,
    const float* __restrict__ agent_v, u16* __restrict__ attn_out) {
    __shared__ float qtile[64 * 64];   // slot-swizzled rows
    __shared__ float atile[49 * 64];
    __shared__ float av[49 * 64];
    __shared__ float PT[49 * 64];      // PT[a][i]
    __shared__ float spart[4][64];
    __shared__ float sinv[64];
    const int ntile = blockIdx.x;      // 0..48
    const int bh = blockIdx.y;
    const int b = bh / 12, h = bh - b * 12;
    const int t = threadIdx.x, lane = t & 63, w = t >> 6;
    const int n0 = ntile * 64;
    const float* atsrc = at + (size_t)b * 49 * 768 + h * 64;
    for (int e = t; e < 49 * 64; e += 256) {
        atile[e] = atsrc[(size_t)(e >> 6) * 768 + (e & 63)];
        av[e] = agent_v[(size_t)bh * 3136 + e];
    }
    {
        const int si = t >> 2, sseg = t & 3;
        const u16* qp = qkv + ((size_t)(b * 3136 + n0 + si)) * 2304 + h * 64 + sseg * 16;
        u16x8 q0 = *(const u16x8*)qp, q1 = *(const u16x8*)(qp + 8);
        #pragma unroll
        for (int half = 0; half < 2; ++half) {
            u16x8 qq = half ? q1 : q0;
            #pragma unroll
            for (int q2 = 0; q2 < 2; ++q2) {
                int sl = sseg * 4 + half * 2 + q2;
                int col = ((sl ^ (si & 7)) << 2);
                f32x4 qf = { b2f(qq[q2*4+0]), b2f(qq[q2*4+1]), b2f(qq[q2*4+2]), b2f(qq[q2*4+3]) };
                *(f32x4*)&qtile[si * 64 + col] = qf;
            }
        }
    }
    __syncthreads();
    // logits + exp + partial sums: lane = position i, quarter w -> agents w*13..
    {
        float ssum = 0.f;
        #pragma unroll
        for (int idx = 0; idx < 13; ++idx) {
            int a = w * 13 + idx;
            if (a < 49) {
                f32x4 acc4 = {0.f, 0.f, 0.f, 0.f};
                #pragma unroll
                for (int sl = 0; sl < 16; ++sl) {
                    f32x4 at4 = *(const f32x4*)&atile[a * 64 + sl * 4];
                    f32x4 q4 = *(const f32x4*)&qtile[lane * 64 + ((sl ^ (lane & 7)) << 2)];
                    acc4 += at4 * q4;
                }
                float pexp = __expf(acc4[0] + acc4[1] + acc4[2] + acc4[3]);
                PT[a * 64 + lane] = pexp;
                ssum += pexp;
            }
        }
        spart[w][lane] = ssum;
    }
    __syncthreads();
    if (t < 64) sinv[t] = 1.0f / (spart[0][t] + spart[1][t] + spart[2][t] + spart[3][t]);
    __syncthreads();
    // out: lane = head-dim d, quarter w -> positions i = w*16 + ii
    float acc[16];
    #pragma unroll
    for (int ii = 0; ii < 16; ++ii) acc[ii] = 0.f;
    for (int a = 0; a < 49; ++a) {
        float vv = av[a * 64 + lane];
        #pragma unroll
        for (int i4 = 0; i4 < 4; ++i4) {
            f32x4 p4 = *(const f32x4*)&PT[a * 64 + w * 16 + i4 * 4];
            acc[i4*4+0] += p4[0] * vv;
            acc[i4*4+1] += p4[1] * vv;
            acc[i4*4+2] += p4[2] * vv;
            acc[i4*4+3] += p4[3] * vv;
        }
    }
    const size_t orow = ((size_t)b * 3136 + n0 + w * 16) * 768 + h * 64 + lane;
    #pragma unroll
    for (int ii = 0; ii < 16; ++ii) {
        float o = acc[ii] * sinv[w * 16 + ii];
        attn_out[orow + (size_t)ii * 768] = f2b(o);
    }
}

// ---------------------------------------------------------------------------
extern "C" void kernel_launch(void* const* d_in, const int* in_sizes, int n_in,
                              void* d_out, int out_size, void* d_ws, size_t ws_size,
                              hipStream_t stream) {
    (void)in_sizes; (void)n_in; (void)out_size; (void)ws_size;
    const float* x     = (const float*)d_in[0];
    const float* y     = (const float*)d_in[1];
    const float* ln1w  = (const float*)d_in[2];
    const float* ln1b  = (const float*)d_in[3];
    const float* ln2w  = (const float*)d_in[4];
    const float* ln2b  = (const float*)d_in[5];
    const float* wq1   = (const float*)d_in[6];
    const float* wq2   = (const float*)d_in[7];
    const float* wkv   = (const float*)d_in[8];
    const float* wproj = (const float*)d_in[9];
    const float* bproj = (const float*)d_in[10];
    float* out = (float*)d_out;

    char* ws = (char*)d_ws;
    // workspace layout (bytes); xn is reused as attn_out after qkv GEMM
    u16*   xn      = (u16*)(ws);                      // 25088*768*2  = 38,535,168
    u16*   qkv     = (u16*)(ws + 38535168);           // 25088*2304*2 = 115,605,504
    u16*   wcat    = (u16*)(ws + 154140672);          // 2304*768*2   = 3,538,944
    u16*   wq2T    = (u16*)(ws + 157679616);          // 1,179,648
    u16*   wpb     = (u16*)(ws + 158859264);          // 1,179,648
    float* ypool   = (float*)(ws + 160038912);        // 1,204,224
    float* at      = (float*)(ws + 161243136);        // 1,204,224
    float* ps      = (float*)(ws + 162447360);        // 131,712
    float* pav     = (float*)(ws + 162579072);        // 8,429,568
    float* agent_v = (float*)(ws + 171008640);        // 1,204,224
    u16*   attn_out = xn;

    pack_w_kernel<<<dim3(2304), dim3(256), 0, stream>>>(wq1, wq2, wkv, wproj, wcat, wq2T, wpb);
    ln_x_kernel<<<dim3(392), dim3(256), 0, stream>>>(x, ln1w, ln1b, xn);
    ln_y_pool_kernel<<<dim3(392), dim3(256), 0, stream>>>(y, ln2w, ln2b, ypool);
    gemm_bt_kernel<false><<<dim3(18, 196), dim3(256), 0, stream>>>(xn, wcat, qkv, nullptr, nullptr, 2304);
    at_gemm_kernel<<<dim3(168), dim3(256), 0, stream>>>(ypool, wq2T, at);
    agent_attn_kernel<<<dim3(7, 96), dim3(256), 0, stream>>>(at, qkv, ps, pav);
    combine_kernel<<<dim3(96), dim3(256), 0, stream>>>(ps, pav, agent_v);
    q_attn_kernel<<<dim3(49, 96), dim3(256), 0, stream>>>(at, qkv, agent_v, attn_out);
    gemm_bt_kernel<true><<<dim3(6, 196), dim3(256), 0, stream>>>(attn_out, wpb, nullptr, out, bproj, 768);
}

// Round 2
// 808.026 us; speedup vs baseline: 1.1098x; 1.1098x over previous
//
#include <hip/hip_runtime.h>

typedef unsigned short u16;
typedef u16 u16x8 __attribute__((ext_vector_type(8)));
typedef __bf16 bf16x8 __attribute__((ext_vector_type(8)));
typedef float f32x4 __attribute__((ext_vector_type(4)));

__device__ __forceinline__ float b2f(u16 u) {
    union { unsigned int i; float f; } v; v.i = ((unsigned int)u) << 16; return v.f;
}
__device__ __forceinline__ u16 f2b(float f) {
    union { float f; unsigned int i; } v; v.f = f;
    unsigned int r = v.i + 0x7fffu + ((v.i >> 16) & 1u);
    return (u16)(r >> 16);
}
__device__ __forceinline__ void gload_lds16(const u16* g, u16* l) {
    __builtin_amdgcn_global_load_lds(
        (const __attribute__((address_space(1))) void*)g,
        (__attribute__((address_space(3))) void*)l, 16, 0, 0);
}

// ---------------------------------------------------------------------------
// Pack weights to bf16. wcat = [wq1*scale ; wkv_k*scale ; wkv_v] (2304x768).
// wq2T = wq2 transposed (k-major). wpb = wproj. scale = hd^-0.5 folded in.
// ---------------------------------------------------------------------------
__global__ __launch_bounds__(256) void pack_w_kernel(
    const float* __restrict__ wq1, const float* __restrict__ wq2,
    const float* __restrict__ wkv, const float* __restrict__ wproj,
    u16* __restrict__ wcat, u16* __restrict__ wq2T, u16* __restrict__ wpb) {
    int e = blockIdx.x * 256 + threadIdx.x;   // grid covers exactly 768*768
    const float scale = 0.125f;
    int o = e / 768, c = e - o * 768;
    wcat[e]           = f2b(wq1[e] * scale);
    wcat[589824 + e]  = f2b(wkv[e] * scale);
    wcat[1179648 + e] = f2b(wkv[589824 + e]);
    wq2T[c * 768 + o] = f2b(wq2[e]);
    wpb[e]            = f2b(wproj[e]);
}

// ---------------------------------------------------------------------------
// LN over channel dim of x (b,c,h*w) -> xn (b, n, c) bf16, LDS-transposed.
// ---------------------------------------------------------------------------
__global__ __launch_bounds__(256) void ln_x_kernel(
    const float* __restrict__ x, const float* __restrict__ lw,
    const float* __restrict__ lb, u16* __restrict__ xn) {
    __shared__ float red[8][64];
    __shared__ float smu[64];
    __shared__ float srs[64];
    __shared__ float tl[64][65];
    const int bx = blockIdx.x;
    const int b = bx / 49, tile = bx - b * 49;
    const int pos0 = tile * 64;
    const int t = threadIdx.x;
    const int p = t & 63, q = t >> 6;
    const float* xb = x + (size_t)b * 2408448 + pos0;
    float s = 0.f, s2 = 0.f;
    for (int c = q; c < 768; c += 4) {
        float v = xb[(size_t)c * 3136 + p];
        s += v; s2 += v * v;
    }
    red[q][p] = s; red[4 + q][p] = s2;
    __syncthreads();
    if (t < 64) {
        float ss = red[0][t] + red[1][t] + red[2][t] + red[3][t];
        float qq = red[4][t] + red[5][t] + red[6][t] + red[7][t];
        float mu = ss * (1.0f / 768.0f);
        float var = qq * (1.0f / 768.0f) - mu * mu;
        smu[t] = mu;
        srs[t] = rsqrtf(var + 1e-5f);
    }
    __syncthreads();
    const size_t orow0 = ((size_t)b * 3136 + pos0) * 768;
    for (int ctile = 0; ctile < 12; ++ctile) {
        const int c0 = ctile * 64;
        #pragma unroll
        for (int ii = 0; ii < 16; ++ii) {
            int ci = q + ii * 4;
            tl[ci][p] = xb[(size_t)(c0 + ci) * 3136 + p];
        }
        __syncthreads();
        const float wv = lw[c0 + p], bv = lb[c0 + p];
        #pragma unroll
        for (int ii = 0; ii < 16; ++ii) {
            int pi = q + ii * 4;
            float v = tl[p][pi];
            float nv = (v - smu[pi]) * srs[pi] * wv + bv;
            xn[orow0 + (size_t)pi * 768 + (c0 + p)] = f2b(nv);
        }
        __syncthreads();
    }
}

// ---------------------------------------------------------------------------
// y LN stats per position: rs = rsqrt(var+eps), mrs = mu*rs. Coalesced.
// ---------------------------------------------------------------------------
__global__ __launch_bounds__(256) void y_stats_kernel(
    const float* __restrict__ y, float* __restrict__ rsb, float* __restrict__ mrsb) {
    __shared__ float red[8][64];
    const int bx = blockIdx.x;
    const int b = bx / 49, tile = bx - b * 49;
    const int pos0 = tile * 64;
    const int t = threadIdx.x, p = t & 63, q = t >> 6;
    const float* yb = y + (size_t)b * 2408448 + pos0;
    float s = 0.f, s2 = 0.f;
    for (int c = q; c < 768; c += 4) {
        float v = yb[(size_t)c * 3136 + p];
        s += v; s2 += v * v;
    }
    red[q][p] = s; red[4 + q][p] = s2;
    __syncthreads();
    if (t < 64) {
        float ss = red[0][t] + red[1][t] + red[2][t] + red[3][t];
        float qq = red[4][t] + red[5][t] + red[6][t] + red[7][t];
        float mu = ss * (1.0f / 768.0f);
        float var = qq * (1.0f / 768.0f) - mu * mu;
        float r = rsqrtf(var + 1e-5f);
        rsb[(size_t)b * 3136 + pos0 + t] = r;
        mrsb[(size_t)b * 3136 + pos0 + t] = mu * r;
    }
}

// ---------------------------------------------------------------------------
// Pool of LN(y): ypool[b][a][c] = lw[c]*(sum_p y*rs - sum_p mu*rs)/64 + lb[c].
// Block = (64-channel group, (b, pool-row)). A pool-row's 448 positions are
// CONTIGUOUS in memory. Lane map p = (lane>>3)*56 + it*8 + (lane&7) makes
// iteration `it` exactly agent `it`: full-wave butterfly = pooled sum.
// ---------------------------------------------------------------------------
__global__ __launch_bounds__(256) void y_pool_kernel(
    const float* __restrict__ y, const float* __restrict__ lw,
    const float* __restrict__ lb, const float* __restrict__ rsb,
    const float* __restrict__ mrsb, float* __restrict__ ypool) {
    const int cgrp = blockIdx.x;     // 0..11 (64 channels)
    const int bpi  = blockIdx.y;     // 0..55
    const int b = bpi / 7, pi = bpi - b * 7;
    const int t = threadIdx.x, lane = t & 63, w = t >> 6;
    const int pbase = b * 3136 + pi * 448;
    const int p0 = (lane >> 3) * 56 + (lane & 7);
    float rsv[7], s3f[7];
    #pragma unroll
    for (int it = 0; it < 7; ++it) {
        rsv[it] = rsb[pbase + p0 + it * 8];
        float m = mrsb[pbase + p0 + it * 8];
        #pragma unroll
        for (int msk = 1; msk < 64; msk <<= 1) m += __shfl_xor(m, msk, 64);
        s3f[it] = m;
    }
    const float* yb = y + (size_t)b * 2408448 + pi * 448 + p0;
    float* yo = ypool + ((size_t)b * 49 + pi * 7) * 768;
    for (int ci = 0; ci < 16; ++ci) {
        const int c = cgrp * 64 + w * 16 + ci;
        const float* yc = yb + (size_t)c * 3136;
        float v[7];
        #pragma unroll
        for (int it = 0; it < 7; ++it) v[it] = yc[it * 8] * rsv[it];
        #pragma unroll
        for (int it = 0; it < 7; ++it) {
            float s = v[it];
            #pragma unroll
            for (int msk = 1; msk < 64; msk <<= 1) s += __shfl_xor(s, msk, 64);
            v[it] = s;
        }
        if (lane == 0) {
            const float wv = lw[c], bv = lb[c];
            #pragma unroll
            for (int it = 0; it < 7; ++it)
                yo[(size_t)it * 768 + c] = wv * (v[it] - s3f[it]) * (1.0f / 64.0f) + bv;
        }
    }
}

// ---------------------------------------------------------------------------
// bf16 MFMA GEMM, C = A(MxK) * B(NxK)^T. K=768. 128x128 tile, BK=64, 4 waves.
// m97 structure: global_load_lds width=16 staging, linear LDS, 2 barriers/K.
// PROJ=false: C -> bf16 row-major. PROJ=true: f32 +bias transposed (b,o,n).
// ---------------------------------------------------------------------------
template<bool PROJ>
__global__ __launch_bounds__(256) void gemm_bt_kernel(
    const u16* __restrict__ A, const u16* __restrict__ B,
    u16* __restrict__ Cb, float* __restrict__ Cf,
    const float* __restrict__ bias, int N) {
    __shared__ u16 As[128 * 64];
    __shared__ u16 Bs[128 * 64];
    const int t = threadIdx.x;
    const int lane = t & 63;
    const int w = t >> 6;
    const int wr = w >> 1, wc = w & 1;
    const int ct = blockIdx.x, rt = blockIdx.y;
    const u16* Ab = A + (size_t)rt * 128 * 768;
    const u16* Bb = B + (size_t)ct * 128 * 768;
    const int grh = lane >> 3;            // 0..7: row within 8-row chunk
    const int gcol = (lane & 7) * 8;      // 16B column within 64-wide k-slab

    f32x4 acc[4][4];
    #pragma unroll
    for (int mi = 0; mi < 4; ++mi)
        #pragma unroll
        for (int ni = 0; ni < 4; ++ni)
            acc[mi][ni] = (f32x4){0.f, 0.f, 0.f, 0.f};

    for (int kt = 0; kt < 12; ++kt) {
        if (kt) __syncthreads();          // previous compute done before overwrite
        #pragma unroll
        for (int i = 0; i < 4; ++i) {
            const int chunk = w * 4 + i;              // 0..15, wave-uniform
            const int row = chunk * 8 + grh;
            gload_lds16(Ab + (size_t)row * 768 + kt * 64 + gcol, &As[chunk * 512]);
            gload_lds16(Bb + (size_t)row * 768 + kt * 64 + gcol, &Bs[chunk * 512]);
        }
        __syncthreads();                  // drains vmcnt before compute
        #pragma unroll
        for (int ks = 0; ks < 2; ++ks) {
            const int koff = ks * 32 + (lane >> 4) * 8;
            bf16x8 af[4], bfv[4];
            #pragma unroll
            for (int mi = 0; mi < 4; ++mi)
                af[mi] = *(const bf16x8*)&As[(wr * 64 + mi * 16 + (lane & 15)) * 64 + koff];
            #pragma unroll
            for (int ni = 0; ni < 4; ++ni)
                bfv[ni] = *(const bf16x8*)&Bs[(wc * 64 + ni * 16 + (lane & 15)) * 64 + koff];
            #pragma unroll
            for (int mi = 0; mi < 4; ++mi)
                #pragma unroll
                for (int ni = 0; ni < 4; ++ni)
                    acc[mi][ni] = __builtin_amdgcn_mfma_f32_16x16x32_bf16(
                        af[mi], bfv[ni], acc[mi][ni], 0, 0, 0);
        }
    }

    if constexpr (!PROJ) {
        #pragma unroll
        for (int mi = 0; mi < 4; ++mi)
            #pragma unroll
            for (int ni = 0; ni < 4; ++ni) {
                int row0 = rt * 128 + wr * 64 + mi * 16 + (lane >> 4) * 4;
                int col = ct * 128 + wc * 64 + ni * 16 + (lane & 15);
                #pragma unroll
                for (int r = 0; r < 4; ++r)
                    Cb[(size_t)(row0 + r) * N + col] = f2b(acc[mi][ni][r]);
            }
    } else {
        #pragma unroll
        for (int ni = 0; ni < 4; ++ni) {
            int col = ct * 128 + wc * 64 + ni * 16 + (lane & 15);   // output channel o
            float bv = bias[col];
            #pragma unroll
            for (int mi = 0; mi < 4; ++mi) {
                int grow = rt * 128 + wr * 64 + mi * 16 + (lane >> 4) * 4; // 4 consec n
                int bb = grow / 3136;
                int nn = grow - bb * 3136;
                f32x4 vv = acc[mi][ni];
                vv[0] += bv; vv[1] += bv; vv[2] += bv; vv[3] += bv;
                *(f32x4*)(Cf + (size_t)bb * 2408448 + (size_t)col * 3136 + nn) = vv;
            }
        }
    }
}

// ---------------------------------------------------------------------------
// agent_tokens = ypool @ wq2T : (8*49) x 768, K=768. Small GEMM, f32 out.
// ---------------------------------------------------------------------------
__global__ __launch_bounds__(256) void at_gemm_kernel(
    const float* __restrict__ ypool, const u16* __restrict__ wq2T,
    float* __restrict__ at) {
    __shared__ float y7[7][768];
    const int bx = blockIdx.x;     // b*21 + ag*3 + nt
    const int b = bx / 21, rem = bx - b * 21;
    const int ag = rem / 3, nt = rem - ag * 3;
    const int t = threadIdx.x;
    const int abase = ag * 7;
    const float* ysrc = ypool + ((size_t)b * 49 + abase) * 768;
    for (int e = t; e < 7 * 768; e += 256) y7[e / 768][e % 768] = ysrc[e];
    __syncthreads();
    const int n = nt * 256 + t;
    float acc[7];
    #pragma unroll
    for (int j = 0; j < 7; ++j) acc[j] = 0.f;
    for (int k = 0; k < 768; ++k) {
        float wv = b2f(wq2T[(size_t)k * 768 + n]);
        #pragma unroll
        for (int j = 0; j < 7; ++j) acc[j] += y7[j][k] * wv;
    }
    #pragma unroll
    for (int j = 0; j < 7; ++j)
        at[((size_t)b * 49 + abase + j) * 768 + n] = acc[j];
}

// ---------------------------------------------------------------------------
// Agent-side attention, n-split into 7 partials per (b,h).
// ---------------------------------------------------------------------------
__global__ __launch_bounds__(256) void agent_attn_kernel(
    const float* __restrict__ at, const u16* __restrict__ qkv,
    float* __restrict__ ps, float* __restrict__ pav) {
    __shared__ float atile[49 * 64];
    __shared__ float ktile[64 * 64];   // slot-swizzled rows
    __shared__ float vtile[64 * 64];   // slot-swizzled rows
    __shared__ float P[49 * 64];       // P[a][i]
    __shared__ float sA[49];
    const int ns = blockIdx.x;         // 0..6
    const int bh = blockIdx.y;         // 0..95
    const int b = bh / 12, h = bh - b * 12;
    const int t = threadIdx.x, lane = t & 63, w = t >> 6;
    const float* atsrc = at + (size_t)b * 49 * 768 + h * 64;
    for (int e = t; e < 49 * 64; e += 256)
        atile[e] = atsrc[(size_t)(e >> 6) * 768 + (e & 63)];
    if (t < 49) sA[t] = 0.f;
    float accv[13];
    #pragma unroll
    for (int i = 0; i < 13; ++i) accv[i] = 0.f;
    const int si = t >> 2, sseg = t & 3;

    for (int tile = 0; tile < 7; ++tile) {
        const int n0 = ns * 448 + tile * 64;
        {   // stage k,v (16 bf16 each per thread), swizzled f32x4 slots
            const u16* kp = qkv + ((size_t)(b * 3136 + n0 + si)) * 2304 + 768 + h * 64 + sseg * 16;
            u16x8 k0 = *(const u16x8*)kp, k1 = *(const u16x8*)(kp + 8);
            u16x8 v0 = *(const u16x8*)(kp + 768), v1 = *(const u16x8*)(kp + 776);
            #pragma unroll
            for (int half = 0; half < 2; ++half) {
                u16x8 kk = half ? k1 : k0;
                u16x8 vv = half ? v1 : v0;
                #pragma unroll
                for (int q2 = 0; q2 < 2; ++q2) {
                    int sl = sseg * 4 + half * 2 + q2;
                    int col = ((sl ^ (si & 7)) << 2);
                    f32x4 kf = { b2f(kk[q2*4+0]), b2f(kk[q2*4+1]), b2f(kk[q2*4+2]), b2f(kk[q2*4+3]) };
                    f32x4 vf = { b2f(vv[q2*4+0]), b2f(vv[q2*4+1]), b2f(vv[q2*4+2]), b2f(vv[q2*4+3]) };
                    *(f32x4*)&ktile[si * 64 + col] = kf;
                    *(f32x4*)&vtile[si * 64 + col] = vf;
                }
            }
        }
        __syncthreads();
        #pragma unroll
        for (int idx = 0; idx < 13; ++idx) {
            int a = w + idx * 4;
            if (a < 49) {
                f32x4 acc4 = {0.f, 0.f, 0.f, 0.f};
                #pragma unroll
                for (int sl = 0; sl < 16; ++sl) {
                    f32x4 at4 = *(const f32x4*)&atile[a * 64 + sl * 4];
                    f32x4 k4 = *(const f32x4*)&ktile[lane * 64 + ((sl ^ (lane & 7)) << 2)];
                    acc4 += at4 * k4;
                }
                float pexp = __expf(acc4[0] + acc4[1] + acc4[2] + acc4[3]);
                P[a * 64 + lane] = pexp;
                float rs_ = pexp;
                #pragma unroll
                for (int m = 1; m < 64; m <<= 1) rs_ += __shfl_xor(rs_, m, 64);
                if (lane == 0) sA[a] += rs_;
            }
        }
        __syncthreads();
        #pragma unroll
        for (int i0 = 0; i0 < 64; i0 += 4) {
            float vr[4];
            #pragma unroll
            for (int ii = 0; ii < 4; ++ii) {
                int row = i0 + ii;
                vr[ii] = vtile[row * 64 + ((((lane >> 2) ^ (row & 7)) << 2) | (lane & 3))];
            }
            #pragma unroll
            for (int idx = 0; idx < 13; ++idx) {
                int a = w + idx * 4;
                if (a < 49) {
                    f32x4 p4 = *(const f32x4*)&P[a * 64 + i0];
                    accv[idx] += p4[0]*vr[0] + p4[1]*vr[1] + p4[2]*vr[2] + p4[3]*vr[3];
                }
            }
        }
        __syncthreads();
    }
    const size_t pbase = ((size_t)bh * 7 + ns) * 49;
    if (t < 49) ps[pbase + t] = sA[t];
    #pragma unroll
    for (int idx = 0; idx < 13; ++idx) {
        int a = w + idx * 4;
        if (a < 49) pav[(pbase + a) * 64 + lane] = accv[idx];
    }
}

__global__ __launch_bounds__(256) void combine_kernel(
    const float* __restrict__ ps, const float* __restrict__ pav,
    float* __restrict__ agent_v) {
    const int bh = blockIdx.x;
    const int t = threadIdx.x, lane = t & 63, w = t >> 6;
    for (int a = w; a < 49; a += 4) {
        float s = 0.f, vsum = 0.f;
        #pragma unroll
        for (int ns = 0; ns < 7; ++ns) {
            size_t pb = ((size_t)bh * 7 + ns) * 49 + a;
            s += ps[pb];
            vsum += pav[pb * 64 + lane];
        }
        agent_v[((size_t)bh * 49 + a) * 64 + lane] = vsum / s;
    }
}

// ---------------------------------------------------------------------------
// Q-side attention per (b,h, 64-position tile).
// ---------------------------------------------------------------------------
__global__ __launch_bounds__(256) void q_attn_kernel(
    const float* __restrict__ at, const u16* __restrict__ qkv,
    const float* __restrict__ agent_v, u16* __restrict__ attn_out) {
    __shared__ float qtile[64 * 64];   // slot-swizzled rows
    __shared__ float atile[49 * 64];
    __shared__ float av[49 * 64];
    __shared__ float PT[49 * 64];      // PT[a][i]
    __shared__ float spart[4][64];
    __shared__ float sinv[64];
    const int ntile = blockIdx.x;      // 0..48
    const int bh = blockIdx.y;
    const int b = bh / 12, h = bh - b * 12;
    const int t = threadIdx.x, lane = t & 63, w = t >> 6;
    const int n0 = ntile * 64;
    const float* atsrc = at + (size_t)b * 49 * 768 + h * 64;
    for (int e = t; e < 49 * 64; e += 256) {
        atile[e] = atsrc[(size_t)(e >> 6) * 768 + (e & 63)];
        av[e] = agent_v[(size_t)bh * 3136 + e];
    }
    {
        const int si = t >> 2, sseg = t & 3;
        const u16* qp = qkv + ((size_t)(b * 3136 + n0 + si)) * 2304 + h * 64 + sseg * 16;
        u16x8 q0 = *(const u16x8*)qp, q1 = *(const u16x8*)(qp + 8);
        #pragma unroll
        for (int half = 0; half < 2; ++half) {
            u16x8 qq = half ? q1 : q0;
            #pragma unroll
            for (int q2 = 0; q2 < 2; ++q2) {
                int sl = sseg * 4 + half * 2 + q2;
                int col = ((sl ^ (si & 7)) << 2);
                f32x4 qf = { b2f(qq[q2*4+0]), b2f(qq[q2*4+1]), b2f(qq[q2*4+2]), b2f(qq[q2*4+3]) };
                *(f32x4*)&qtile[si * 64 + col] = qf;
            }
        }
    }
    __syncthreads();
    {
        float ssum = 0.f;
        #pragma unroll
        for (int idx = 0; idx < 13; ++idx) {
            int a = w * 13 + idx;
            if (a < 49) {
                f32x4 acc4 = {0.f, 0.f, 0.f, 0.f};
                #pragma unroll
                for (int sl = 0; sl < 16; ++sl) {
                    f32x4 at4 = *(const f32x4*)&atile[a * 64 + sl * 4];
                    f32x4 q4 = *(const f32x4*)&qtile[lane * 64 + ((sl ^ (lane & 7)) << 2)];
                    acc4 += at4 * q4;
                }
                float pexp = __expf(acc4[0] + acc4[1] + acc4[2] + acc4[3]);
                PT[a * 64 + lane] = pexp;
                ssum += pexp;
            }
        }
        spart[w][lane] = ssum;
    }
    __syncthreads();
    if (t < 64) sinv[t] = 1.0f / (spart[0][t] + spart[1][t] + spart[2][t] + spart[3][t]);
    __syncthreads();
    float acc[16];
    #pragma unroll
    for (int ii = 0; ii < 16; ++ii) acc[ii] = 0.f;
    for (int a = 0; a < 49; ++a) {
        float vv = av[a * 64 + lane];
        #pragma unroll
        for (int i4 = 0; i4 < 4; ++i4) {
            f32x4 p4 = *(const f32x4*)&PT[a * 64 + w * 16 + i4 * 4];
            acc[i4*4+0] += p4[0] * vv;
            acc[i4*4+1] += p4[1] * vv;
            acc[i4*4+2] += p4[2] * vv;
            acc[i4*4+3] += p4[3] * vv;
        }
    }
    const size_t orow = ((size_t)b * 3136 + n0 + w * 16) * 768 + h * 64 + lane;
    #pragma unroll
    for (int ii = 0; ii < 16; ++ii) {
        float o = acc[ii] * sinv[w * 16 + ii];
        attn_out[orow + (size_t)ii * 768] = f2b(o);
    }
}

// ---------------------------------------------------------------------------
extern "C" void kernel_launch(void* const* d_in, const int* in_sizes, int n_in,
                              void* d_out, int out_size, void* d_ws, size_t ws_size,
                              hipStream_t stream) {
    (void)in_sizes; (void)n_in; (void)out_size; (void)ws_size;
    const float* x     = (const float*)d_in[0];
    const float* y     = (const float*)d_in[1];
    const float* ln1w  = (const float*)d_in[2];
    const float* ln1b  = (const float*)d_in[3];
    const float* ln2w  = (const float*)d_in[4];
    const float* ln2b  = (const float*)d_in[5];
    const float* wq1   = (const float*)d_in[6];
    const float* wq2   = (const float*)d_in[7];
    const float* wkv   = (const float*)d_in[8];
    const float* wproj = (const float*)d_in[9];
    const float* bproj = (const float*)d_in[10];
    float* out = (float*)d_out;

    char* ws = (char*)d_ws;
    // workspace layout (bytes); xn reused as attn_out; rs/mrs overlap pav
    // (pav written only later by agent_attn, after y_pool consumed rs/mrs)
    u16*   xn      = (u16*)(ws);                      // 38,535,168
    u16*   qkv     = (u16*)(ws + 38535168);           // 115,605,504
    u16*   wcat    = (u16*)(ws + 154140672);          // 3,538,944
    u16*   wq2T    = (u16*)(ws + 157679616);          // 1,179,648
    u16*   wpb     = (u16*)(ws + 158859264);          // 1,179,648
    float* ypool   = (float*)(ws + 160038912);        // 1,204,224
    float* at      = (float*)(ws + 161243136);        // 1,204,224
    float* ps      = (float*)(ws + 162447360);        // 131,712
    float* pav     = (float*)(ws + 162579072);        // 8,429,568
    float* agent_v = (float*)(ws + 171008640);        // 1,204,224
    float* rsb     = (float*)(ws + 162579072);        // 100,352 (overlaps pav)
    float* mrsb    = (float*)(ws + 162679424);        // 100,352 (overlaps pav)
    u16*   attn_out = xn;

    pack_w_kernel<<<dim3(2304), dim3(256), 0, stream>>>(wq1, wq2, wkv, wproj, wcat, wq2T, wpb);
    ln_x_kernel<<<dim3(392), dim3(256), 0, stream>>>(x, ln1w, ln1b, xn);
    y_stats_kernel<<<dim3(392), dim3(256), 0, stream>>>(y, rsb, mrsb);
    y_pool_kernel<<<dim3(12, 56), dim3(256), 0, stream>>>(y, ln2w, ln2b, rsb, mrsb, ypool);
    gemm_bt_kernel<false><<<dim3(18, 196), dim3(256), 0, stream>>>(xn, wcat, qkv, nullptr, nullptr, 2304);
    at_gemm_kernel<<<dim3(168), dim3(256), 0, stream>>>(ypool, wq2T, at);
    agent_attn_kernel<<<dim3(7, 96), dim3(256), 0, stream>>>(at, qkv, ps, pav);
    combine_kernel<<<dim3(96), dim3(256), 0, stream>>>(ps, pav, agent_v);
    q_attn_kernel<<<dim3(49, 96), dim3(256), 0, stream>>>(at, qkv, agent_v, attn_out);
    gemm_bt_kernel<true><<<dim3(6, 196), dim3(256), 0, stream>>>(attn_out, wpb, nullptr, out, bproj, 768);
}

// Round 3
// 544.232 us; speedup vs baseline: 1.6477x; 1.4847x over previous
//
#include <hip/hip_runtime.h>

typedef unsigned short u16;
typedef u16 u16x4 __attribute__((ext_vector_type(4)));
typedef u16 u16x8 __attribute__((ext_vector_type(8)));
typedef __bf16 bf16x8 __attribute__((ext_vector_type(8)));
typedef float f32x4 __attribute__((ext_vector_type(4)));

__device__ __forceinline__ float b2f(u16 u) {
    union { unsigned int i; float f; } v; v.i = ((unsigned int)u) << 16; return v.f;
}
__device__ __forceinline__ u16 f2b(float f) {
    union { float f; unsigned int i; } v; v.f = f;
    unsigned int r = v.i + 0x7fffu + ((v.i >> 16) & 1u);
    return (u16)(r >> 16);
}
__device__ __forceinline__ void gload_lds16(const u16* g, u16* l) {
    __builtin_amdgcn_global_load_lds(
        (const __attribute__((address_space(1))) void*)g,
        (__attribute__((address_space(3))) void*)l, 16, 0, 0);
}
__device__ __forceinline__ bf16x8 ones_frag() {
    union { u16x8 u; bf16x8 b; } v;
    #pragma unroll
    for (int i = 0; i < 8; ++i) v.u[i] = 0x3F80;
    return v.b;
}

// ---------------------------------------------------------------------------
// Pack weights to bf16. wcat = [wq1*scale ; wkv_k*scale ; wkv_v] (2304x768).
// wq2T = wq2 transposed. wpb = wproj. scale = hd^-0.5 folded into q and k.
// ---------------------------------------------------------------------------
__global__ __launch_bounds__(256) void pack_w_kernel(
    const float* __restrict__ wq1, const float* __restrict__ wq2,
    const float* __restrict__ wkv, const float* __restrict__ wproj,
    u16* __restrict__ wcat, u16* __restrict__ wq2T, u16* __restrict__ wpb) {
    int e = blockIdx.x * 256 + threadIdx.x;
    const float scale = 0.125f;
    int o = e / 768, c = e - o * 768;
    wcat[e]           = f2b(wq1[e] * scale);
    wcat[589824 + e]  = f2b(wkv[e] * scale);
    wcat[1179648 + e] = f2b(wkv[589824 + e]);
    wq2T[c * 768 + o] = f2b(wq2[e]);
    wpb[e]            = f2b(wproj[e]);
}

// ---------------------------------------------------------------------------
// LN over channel dim of x (b,c,h*w) -> xn (b, n, c) bf16, LDS-transposed.
// ---------------------------------------------------------------------------
__global__ __launch_bounds__(256) void ln_x_kernel(
    const float* __restrict__ x, const float* __restrict__ lw,
    const float* __restrict__ lb, u16* __restrict__ xn) {
    __shared__ float red[8][64];
    __shared__ float smu[64];
    __shared__ float srs[64];
    __shared__ float tl[64][65];
    const int bx = blockIdx.x;
    const int b = bx / 49, tile = bx - b * 49;
    const int pos0 = tile * 64;
    const int t = threadIdx.x;
    const int p = t & 63, q = t >> 6;
    const float* xb = x + (size_t)b * 2408448 + pos0;
    float s = 0.f, s2 = 0.f;
    for (int c = q; c < 768; c += 4) {
        float v = xb[(size_t)c * 3136 + p];
        s += v; s2 += v * v;
    }
    red[q][p] = s; red[4 + q][p] = s2;
    __syncthreads();
    if (t < 64) {
        float ss = red[0][t] + red[1][t] + red[2][t] + red[3][t];
        float qq = red[4][t] + red[5][t] + red[6][t] + red[7][t];
        float mu = ss * (1.0f / 768.0f);
        float var = qq * (1.0f / 768.0f) - mu * mu;
        smu[t] = mu;
        srs[t] = rsqrtf(var + 1e-5f);
    }
    __syncthreads();
    const size_t orow0 = ((size_t)b * 3136 + pos0) * 768;
    for (int ctile = 0; ctile < 12; ++ctile) {
        const int c0 = ctile * 64;
        #pragma unroll
        for (int ii = 0; ii < 16; ++ii) {
            int ci = q + ii * 4;
            tl[ci][p] = xb[(size_t)(c0 + ci) * 3136 + p];
        }
        __syncthreads();
        const float wv = lw[c0 + p], bv = lb[c0 + p];
        #pragma unroll
        for (int ii = 0; ii < 16; ++ii) {
            int pi = q + ii * 4;
            float v = tl[p][pi];
            float nv = (v - smu[pi]) * srs[pi] * wv + bv;
            xn[orow0 + (size_t)pi * 768 + (c0 + p)] = f2b(nv);
        }
        __syncthreads();
    }
}

// ---------------------------------------------------------------------------
// y LN stats per position: rs = rsqrt(var+eps), mrs = mu*rs. Coalesced.
// ---------------------------------------------------------------------------
__global__ __launch_bounds__(256) void y_stats_kernel(
    const float* __restrict__ y, float* __restrict__ rsb, float* __restrict__ mrsb) {
    __shared__ float red[8][64];
    const int bx = blockIdx.x;
    const int b = bx / 49, tile = bx - b * 49;
    const int pos0 = tile * 64;
    const int t = threadIdx.x, p = t & 63, q = t >> 6;
    const float* yb = y + (size_t)b * 2408448 + pos0;
    float s = 0.f, s2 = 0.f;
    for (int c = q; c < 768; c += 4) {
        float v = yb[(size_t)c * 3136 + p];
        s += v; s2 += v * v;
    }
    red[q][p] = s; red[4 + q][p] = s2;
    __syncthreads();
    if (t < 64) {
        float ss = red[0][t] + red[1][t] + red[2][t] + red[3][t];
        float qq = red[4][t] + red[5][t] + red[6][t] + red[7][t];
        float mu = ss * (1.0f / 768.0f);
        float var = qq * (1.0f / 768.0f) - mu * mu;
        float r = rsqrtf(var + 1e-5f);
        rsb[(size_t)b * 3136 + pos0 + t] = r;
        mrsb[(size_t)b * 3136 + pos0 + t] = mu * r;
    }
}

// ---------------------------------------------------------------------------
// Pool of LN(y) -> ypool (b, 49, 768) f32. Pool-row positions are contiguous.
// ---------------------------------------------------------------------------
__global__ __launch_bounds__(256) void y_pool_kernel(
    const float* __restrict__ y, const float* __restrict__ lw,
    const float* __restrict__ lb, const float* __restrict__ rsb,
    const float* __restrict__ mrsb, float* __restrict__ ypool) {
    const int cgrp = blockIdx.x;     // 0..11
    const int bpi  = blockIdx.y;     // 0..55
    const int b = bpi / 7, pi = bpi - b * 7;
    const int t = threadIdx.x, lane = t & 63, w = t >> 6;
    const int pbase = b * 3136 + pi * 448;
    const int p0 = (lane >> 3) * 56 + (lane & 7);
    float rsv[7], s3f[7];
    #pragma unroll
    for (int it = 0; it < 7; ++it) {
        rsv[it] = rsb[pbase + p0 + it * 8];
        float m = mrsb[pbase + p0 + it * 8];
        #pragma unroll
        for (int msk = 1; msk < 64; msk <<= 1) m += __shfl_xor(m, msk, 64);
        s3f[it] = m;
    }
    const float* yb = y + (size_t)b * 2408448 + pi * 448 + p0;
    float* yo = ypool + ((size_t)b * 49 + pi * 7) * 768;
    for (int ci = 0; ci < 16; ++ci) {
        const int c = cgrp * 64 + w * 16 + ci;
        const float* yc = yb + (size_t)c * 3136;
        float v[7];
        #pragma unroll
        for (int it = 0; it < 7; ++it) v[it] = yc[it * 8] * rsv[it];
        #pragma unroll
        for (int it = 0; it < 7; ++it) {
            float s = v[it];
            #pragma unroll
            for (int msk = 1; msk < 64; msk <<= 1) s += __shfl_xor(s, msk, 64);
            v[it] = s;
        }
        if (lane == 0) {
            const float wv = lw[c], bv = lb[c];
            #pragma unroll
            for (int it = 0; it < 7; ++it)
                yo[(size_t)it * 768 + c] = wv * (v[it] - s3f[it]) * (1.0f / 64.0f) + bv;
        }
    }
}

// ---------------------------------------------------------------------------
// bf16 MFMA GEMM, C = A(Mx768) * B(Nx768)^T. 128x128 tile, m97 structure.
// MODE 0 (qkv): cols <1536 -> qk[n][1536] bf16; cols >=1536 -> V TRANSPOSED
//               vT[(b*768 + c)][n] bf16 (packed 4-bf16 stores along n).
// MODE 1 (proj): f32 +bias, written transposed to (b, o, n).
// ---------------------------------------------------------------------------
template<int MODE>
__global__ __launch_bounds__(256) void gemm_bt_kernel(
    const u16* __restrict__ A, const u16* __restrict__ B,
    u16* __restrict__ qk, u16* __restrict__ vT,
    float* __restrict__ Cf, const float* __restrict__ bias) {
    __shared__ u16 As[128 * 64];
    __shared__ u16 Bs[128 * 64];
    const int t = threadIdx.x;
    const int lane = t & 63;
    const int w = t >> 6;
    const int wr = w >> 1, wc = w & 1;
    const int ct = blockIdx.x, rt = blockIdx.y;
    const u16* Ab = A + (size_t)rt * 128 * 768;
    const u16* Bb = B + (size_t)ct * 128 * 768;
    const int grh = lane >> 3;
    const int gcol = (lane & 7) * 8;

    f32x4 acc[4][4];
    #pragma unroll
    for (int mi = 0; mi < 4; ++mi)
        #pragma unroll
        for (int ni = 0; ni < 4; ++ni)
            acc[mi][ni] = (f32x4){0.f, 0.f, 0.f, 0.f};

    for (int kt = 0; kt < 12; ++kt) {
        if (kt) __syncthreads();
        #pragma unroll
        for (int i = 0; i < 4; ++i) {
            const int chunk = w * 4 + i;
            const int row = chunk * 8 + grh;
            gload_lds16(Ab + (size_t)row * 768 + kt * 64 + gcol, &As[chunk * 512]);
            gload_lds16(Bb + (size_t)row * 768 + kt * 64 + gcol, &Bs[chunk * 512]);
        }
        __syncthreads();
        #pragma unroll
        for (int ks = 0; ks < 2; ++ks) {
            const int koff = ks * 32 + (lane >> 4) * 8;
            bf16x8 af[4], bfv[4];
            #pragma unroll
            for (int mi = 0; mi < 4; ++mi)
                af[mi] = *(const bf16x8*)&As[(wr * 64 + mi * 16 + (lane & 15)) * 64 + koff];
            #pragma unroll
            for (int ni = 0; ni < 4; ++ni)
                bfv[ni] = *(const bf16x8*)&Bs[(wc * 64 + ni * 16 + (lane & 15)) * 64 + koff];
            #pragma unroll
            for (int mi = 0; mi < 4; ++mi)
                #pragma unroll
                for (int ni = 0; ni < 4; ++ni)
                    acc[mi][ni] = __builtin_amdgcn_mfma_f32_16x16x32_bf16(
                        af[mi], bfv[ni], acc[mi][ni], 0, 0, 0);
        }
    }

    if constexpr (MODE == 0) {
        #pragma unroll
        for (int mi = 0; mi < 4; ++mi)
            #pragma unroll
            for (int ni = 0; ni < 4; ++ni) {
                const int row0 = rt * 128 + wr * 64 + mi * 16 + (lane >> 4) * 4;
                const int col = ct * 128 + wc * 64 + ni * 16 + (lane & 15);
                if (col < 1536) {
                    #pragma unroll
                    for (int r = 0; r < 4; ++r)
                        qk[(size_t)(row0 + r) * 1536 + col] = f2b(acc[mi][ni][r]);
                } else {
                    const int c = col - 1536;
                    const int bb = row0 / 3136;
                    const int nn2 = row0 - bb * 3136;
                    u16x4 pk;
                    #pragma unroll
                    for (int r = 0; r < 4; ++r) pk[r] = f2b(acc[mi][ni][r]);
                    *(u16x4*)&vT[((size_t)(bb * 768 + c)) * 3136 + nn2] = pk;
                }
            }
    } else {
        #pragma unroll
        for (int ni = 0; ni < 4; ++ni) {
            const int col = ct * 128 + wc * 64 + ni * 16 + (lane & 15);
            const float bv = bias[col];
            #pragma unroll
            for (int mi = 0; mi < 4; ++mi) {
                const int grow = rt * 128 + wr * 64 + mi * 16 + (lane >> 4) * 4;
                const int bb = grow / 3136;
                const int nn2 = grow - bb * 3136;
                f32x4 vv = acc[mi][ni];
                vv[0] += bv; vv[1] += bv; vv[2] += bv; vv[3] += bv;
                *(f32x4*)(Cf + (size_t)bb * 2408448 + (size_t)col * 3136 + nn2) = vv;
            }
        }
    }
}

// ---------------------------------------------------------------------------
// agent_tokens = ypool @ wq2T -> at_bf (b, 64, 768) bf16, rows 49..63 zeroed.
// ---------------------------------------------------------------------------
__global__ __launch_bounds__(256) void at_gemm_kernel(
    const float* __restrict__ ypool, const u16* __restrict__ wq2T,
    u16* __restrict__ at_bf) {
    __shared__ float y7[7][768];
    const int bx = blockIdx.x;     // b*21 + ag*3 + nt
    const int b = bx / 21, rem = bx - b * 21;
    const int ag = rem / 3, nt = rem - ag * 3;
    const int t = threadIdx.x;
    const int abase = ag * 7;
    const float* ysrc = ypool + ((size_t)b * 49 + abase) * 768;
    for (int e = t; e < 7 * 768; e += 256) y7[e / 768][e % 768] = ysrc[e];
    __syncthreads();
    const int n = nt * 256 + t;
    float acc[7];
    #pragma unroll
    for (int j = 0; j < 7; ++j) acc[j] = 0.f;
    for (int k = 0; k < 768; ++k) {
        float wv = b2f(wq2T[(size_t)k * 768 + n]);
        #pragma unroll
        for (int j = 0; j < 7; ++j) acc[j] += y7[j][k] * wv;
    }
    #pragma unroll
    for (int j = 0; j < 7; ++j)
        at_bf[((size_t)b * 64 + abase + j) * 768 + n] = f2b(acc[j]);
    if (ag == 6) {
        #pragma unroll
        for (int j2 = 0; j2 < 15; ++j2)
            at_bf[((size_t)b * 64 + 49 + j2) * 768 + n] = 0;
    }
}

// ---------------------------------------------------------------------------
// Agent-side attention (MFMA), n-split x7 partials per (b,h).
// S^T = K.at^T  ->  P^T in regs (col=a, rows=n') -> packed P_lds[a][n'].
// PV: O[a][d] = P.V with vT tile; den[a] via ones-MFMA. No shuffles.
// ---------------------------------------------------------------------------
__global__ __launch_bounds__(256) void agent_attn_kernel(
    const u16* __restrict__ at_bf, const u16* __restrict__ qk,
    const u16* __restrict__ vT, float* __restrict__ ps,
    float* __restrict__ pav_t) {
    __shared__ u16 k_lds[2][64 * 64];    // [n'][d], slot-swizzled
    __shared__ u16 vt_lds[2][64 * 64];   // [d][n'], slot-swizzled
    __shared__ u16 p_lds[64 * 64];       // [a][n'], pair-swizzled
    const int ns = blockIdx.x;           // 0..6
    const int bh = blockIdx.y;           // 0..95
    const int b = bh / 12, h = bh - b * 12;
    const int t = threadIdx.x, lane = t & 63, w = t >> 6;
    const int l15 = lane & 15, l4 = lane >> 4;

    bf16x8 atf[2];
    #pragma unroll
    for (int ks = 0; ks < 2; ++ks)
        atf[ks] = *(const bf16x8*)&at_bf[((size_t)b * 64 + 16 * w + l15) * 768 + h * 64 + ks * 32 + l4 * 8];
    const bf16x8 onef = ones_frag();

    f32x4 acc_o[4], acc_den[4];
    #pragma unroll
    for (int mi = 0; mi < 4; ++mi) {
        acc_o[mi] = (f32x4){0.f, 0.f, 0.f, 0.f};
        acc_den[mi] = (f32x4){0.f, 0.f, 0.f, 0.f};
    }

    auto STAGE = [&](int buf, int tile) {
        const int n0 = ns * 448 + tile * 64;
        #pragma unroll
        for (int p = 0; p < 2; ++p) {
            const int row = p * 32 + w * 8 + (lane >> 3);
            const int sc = ((lane & 7) ^ (row & 7)) * 8;
            gload_lds16(qk + ((size_t)(b * 3136 + n0 + row)) * 1536 + 768 + h * 64 + sc,
                        &k_lds[buf][(p * 32 + w * 8) * 64]);
            gload_lds16(vT + ((size_t)(bh * 64 + row)) * 3136 + n0 + sc,
                        &vt_lds[buf][(p * 32 + w * 8) * 64]);
        }
    };

    STAGE(0, 0);
    for (int tile = 0; tile < 7; ++tile) {
        const int buf = tile & 1;
        __syncthreads();                          // staged tile visible; PV(t-1) done
        if (tile < 6) STAGE(buf ^ 1, tile + 1);   // prefetch next into other buffer
        // S^T = K . at^T
        f32x4 acc_s[4];
        #pragma unroll
        for (int mi = 0; mi < 4; ++mi) acc_s[mi] = (f32x4){0.f, 0.f, 0.f, 0.f};
        #pragma unroll
        for (int ks = 0; ks < 2; ++ks)
            #pragma unroll
            for (int mi = 0; mi < 4; ++mi) {
                const int row = 16 * mi + l15;
                bf16x8 kf = *(const bf16x8*)&k_lds[buf][row * 64 + (((ks * 4 + l4) ^ (row & 7)) * 8)];
                acc_s[mi] = __builtin_amdgcn_mfma_f32_16x16x32_bf16(kf, atf[ks], acc_s[mi], 0, 0, 0);
            }
        // exp + pack -> P_lds[a][n']
        const int a_w = 16 * w + l15;
        #pragma unroll
        for (int mi = 0; mi < 4; ++mi) {
            u16x4 pk;
            #pragma unroll
            for (int r = 0; r < 4; ++r) pk[r] = f2b(__expf(acc_s[mi][r]));
            const int pp = (2 * mi + (l4 >> 1)) ^ (a_w & 7);
            *(u16x4*)((char*)p_lds + a_w * 128 + pp * 16 + (l4 & 1) * 8) = pk;
        }
        __syncthreads();                          // P visible
        // PV + den
        #pragma unroll
        for (int ks = 0; ks < 2; ++ks) {
            const int d = 16 * w + l15;
            bf16x8 vf = *(const bf16x8*)&vt_lds[buf][d * 64 + (((ks * 4 + l4) ^ (d & 7)) * 8)];
            #pragma unroll
            for (int mi = 0; mi < 4; ++mi) {
                const int a = 16 * mi + l15;
                bf16x8 pf = *(const bf16x8*)((char*)p_lds + a * 128 + (((ks * 4 + l4) ^ (a & 7)) * 16));
                acc_o[mi] = __builtin_amdgcn_mfma_f32_16x16x32_bf16(pf, vf, acc_o[mi], 0, 0, 0);
                acc_den[mi] = __builtin_amdgcn_mfma_f32_16x16x32_bf16(onef, pf, acc_den[mi], 0, 0, 0);
            }
        }
    }
    const size_t pbase = (size_t)bh * 7 + ns;
    if (w == 0 && lane < 16) {
        #pragma unroll
        for (int mi = 0; mi < 4; ++mi)
            ps[pbase * 64 + 16 * mi + lane] = acc_den[mi][0];
    }
    #pragma unroll
    for (int mi = 0; mi < 4; ++mi)
        *(f32x4*)&pav_t[(pbase * 64 + 16 * w + l15) * 64 + 16 * mi + l4 * 4] = acc_o[mi];
}

// ---------------------------------------------------------------------------
// Combine partials -> av_t (bh, d, a) bf16 (transposed agent_v, q-side B op).
// ---------------------------------------------------------------------------
__global__ __launch_bounds__(256) void combine_kernel(
    const float* __restrict__ ps, const float* __restrict__ pav_t,
    u16* __restrict__ av_t) {
    __shared__ float sinv[64];
    const int bh = blockIdx.x;
    const int t = threadIdx.x;
    if (t < 64) {
        float s = 0.f;
        #pragma unroll
        for (int ns = 0; ns < 7; ++ns) s += ps[((size_t)bh * 7 + ns) * 64 + t];
        sinv[t] = 1.0f / s;
    }
    __syncthreads();
    const int d = t >> 2, aseg = t & 3;
    f32x4 acc[4];
    #pragma unroll
    for (int g = 0; g < 4; ++g) acc[g] = (f32x4){0.f, 0.f, 0.f, 0.f};
    #pragma unroll
    for (int ns = 0; ns < 7; ++ns) {
        const float* src = pav_t + (((size_t)bh * 7 + ns) * 64 + d) * 64 + aseg * 16;
        #pragma unroll
        for (int g = 0; g < 4; ++g) acc[g] += *(const f32x4*)&src[g * 4];
    }
    u16x8 o0, o1;
    #pragma unroll
    for (int g = 0; g < 4; ++g)
        #pragma unroll
        for (int j = 0; j < 4; ++j) {
            const u16 v = f2b(acc[g][j] * sinv[aseg * 16 + g * 4 + j]);
            if (g < 2) o0[g * 4 + j] = v; else o1[(g - 2) * 4 + j] = v;
        }
    u16* dst = av_t + ((size_t)bh * 64 + d) * 64 + aseg * 16;
    *(u16x8*)dst = o0;
    *(u16x8*)(dst + 8) = o1;
}

// ---------------------------------------------------------------------------
// Q-side attention (MFMA) per (b,h, 64-position tile).
// L^T = at.q^T -> P^T regs -> packed P_lds[n][a]; O^T = av^T.P^T -> packed
// 8B stores along c. den via ones-MFMA (same lane-col as O^T). a>=49 masked.
// ---------------------------------------------------------------------------
__global__ __launch_bounds__(256) void q_attn_kernel(
    const u16* __restrict__ at_bf, const u16* __restrict__ qk,
    const u16* __restrict__ av_t, u16* __restrict__ attn_out) {
    __shared__ u16 q_lds[64 * 64];   // [n][d], slot-swizzled
    __shared__ u16 p_lds[64 * 64];   // [n][a], pair-swizzled
    const int ntile = blockIdx.x;    // 0..48
    const int bh = blockIdx.y;       // 0..95
    const int b = bh / 12, h = bh - b * 12;
    const int t = threadIdx.x, lane = t & 63, w = t >> 6;
    const int l15 = lane & 15, l4 = lane >> 4;
    const int n0 = ntile * 64;

    #pragma unroll
    for (int p = 0; p < 2; ++p) {
        const int row = p * 32 + w * 8 + (lane >> 3);
        const int sc = ((lane & 7) ^ (row & 7)) * 8;
        gload_lds16(qk + ((size_t)(b * 3136 + n0 + row)) * 1536 + h * 64 + sc,
                    &q_lds[(p * 32 + w * 8) * 64]);
    }
    bf16x8 atf[4][2], avf[4][2];
    #pragma unroll
    for (int mi = 0; mi < 4; ++mi)
        #pragma unroll
        for (int ks = 0; ks < 2; ++ks) {
            atf[mi][ks] = *(const bf16x8*)&at_bf[((size_t)b * 64 + 16 * mi + l15) * 768 + h * 64 + ks * 32 + l4 * 8];
            avf[mi][ks] = *(const bf16x8*)&av_t[((size_t)bh * 64 + 16 * mi + l15) * 64 + ks * 32 + l4 * 8];
        }
    const bf16x8 onef = ones_frag();
    __syncthreads();

    const int nn = 16 * w + l15;
    f32x4 acc_l[4];
    #pragma unroll
    for (int mi = 0; mi < 4; ++mi) acc_l[mi] = (f32x4){0.f, 0.f, 0.f, 0.f};
    #pragma unroll
    for (int ks = 0; ks < 2; ++ks) {
        bf16x8 qf = *(const bf16x8*)&q_lds[nn * 64 + (((ks * 4 + l4) ^ (nn & 7)) * 8)];
        #pragma unroll
        for (int mi = 0; mi < 4; ++mi)
            acc_l[mi] = __builtin_amdgcn_mfma_f32_16x16x32_bf16(atf[mi][ks], qf, acc_l[mi], 0, 0, 0);
    }
    #pragma unroll
    for (int mi = 0; mi < 4; ++mi) {
        u16x4 pk;
        #pragma unroll
        for (int r = 0; r < 4; ++r) {
            const int a = 16 * mi + l4 * 4 + r;
            pk[r] = (a < 49) ? f2b(__expf(acc_l[mi][r])) : (u16)0;
        }
        const int pp = (2 * mi + (l4 >> 1)) ^ (nn & 7);
        *(u16x4*)((char*)p_lds + nn * 128 + pp * 16 + (l4 & 1) * 8) = pk;
    }
    __syncthreads();

    f32x4 acc_o[4], den;
    #pragma unroll
    for (int mi = 0; mi < 4; ++mi) acc_o[mi] = (f32x4){0.f, 0.f, 0.f, 0.f};
    den = (f32x4){0.f, 0.f, 0.f, 0.f};
    #pragma unroll
    for (int ks = 0; ks < 2; ++ks) {
        bf16x8 pf = *(const bf16x8*)((char*)p_lds + nn * 128 + (((ks * 4 + l4) ^ (nn & 7)) * 16));
        den = __builtin_amdgcn_mfma_f32_16x16x32_bf16(onef, pf, den, 0, 0, 0);
        #pragma unroll
        for (int mi = 0; mi < 4; ++mi)
            acc_o[mi] = __builtin_amdgcn_mfma_f32_16x16x32_bf16(avf[mi][ks], pf, acc_o[mi], 0, 0, 0);
    }
    const float rinv = 1.0f / den[0];
    const size_t obase = ((size_t)(b * 3136 + n0 + nn)) * 768 + h * 64;
    #pragma unroll
    for (int mi = 0; mi < 4; ++mi) {
        u16x4 ov;
        #pragma unroll
        for (int r = 0; r < 4; ++r) ov[r] = f2b(acc_o[mi][r] * rinv);
        *(u16x4*)&attn_out[obase + 16 * mi + l4 * 4] = ov;
    }
}

// ---------------------------------------------------------------------------
extern "C" void kernel_launch(void* const* d_in, const int* in_sizes, int n_in,
                              void* d_out, int out_size, void* d_ws, size_t ws_size,
                              hipStream_t stream) {
    (void)in_sizes; (void)n_in; (void)out_size; (void)ws_size;
    const float* x     = (const float*)d_in[0];
    const float* y     = (const float*)d_in[1];
    const float* ln1w  = (const float*)d_in[2];
    const float* ln1b  = (const float*)d_in[3];
    const float* ln2w  = (const float*)d_in[4];
    const float* ln2b  = (const float*)d_in[5];
    const float* wq1   = (const float*)d_in[6];
    const float* wq2   = (const float*)d_in[7];
    const float* wkv   = (const float*)d_in[8];
    const float* wproj = (const float*)d_in[9];
    const float* bproj = (const float*)d_in[10];
    float* out = (float*)d_out;

    char* ws = (char*)d_ws;
    // Layout (bytes). pav_t lives inside the xn region (xn dead after qkv
    // GEMM; pav_t dead before q_attn writes attn_out back into xn).
    u16*   xn     = (u16*)(ws);                    // 38,535,168
    u16*   qk     = (u16*)(ws + 38535168);         // 77,070,336 ([n][1536])
    u16*   vT     = (u16*)(ws + 115605504);        // 38,535,168 ([b*768+c][n])
    u16*   wcat   = (u16*)(ws + 154140672);        // 3,538,944
    u16*   wq2T   = (u16*)(ws + 157679616);        // 1,179,648
    u16*   wpb    = (u16*)(ws + 158859264);        // 1,179,648
    float* ypool  = (float*)(ws + 160038912);      // 1,204,224
    u16*   at_bf  = (u16*)(ws + 161243136);        // 786,432
    float* ps     = (float*)(ws + 162029568);      // 172,032
    float* rsb    = (float*)(ws + 162201600);      // 100,352
    float* mrsb   = (float*)(ws + 162301952);      // 100,352
    u16*   av_t   = (u16*)(ws + 162402304);        // 786,432 (end 163,188,736)
    float* pav_t  = (float*)(ws);                  // 11,010,048 (in xn region)
    u16*   attn_out = xn;

    pack_w_kernel<<<dim3(2304), dim3(256), 0, stream>>>(wq1, wq2, wkv, wproj, wcat, wq2T, wpb);
    ln_x_kernel<<<dim3(392), dim3(256), 0, stream>>>(x, ln1w, ln1b, xn);
    y_stats_kernel<<<dim3(392), dim3(256), 0, stream>>>(y, rsb, mrsb);
    y_pool_kernel<<<dim3(12, 56), dim3(256), 0, stream>>>(y, ln2w, ln2b, rsb, mrsb, ypool);
    gemm_bt_kernel<0><<<dim3(18, 196), dim3(256), 0, stream>>>(xn, wcat, qk, vT, nullptr, nullptr);
    at_gemm_kernel<<<dim3(168), dim3(256), 0, stream>>>(ypool, wq2T, at_bf);
    agent_attn_kernel<<<dim3(7, 96), dim3(256), 0, stream>>>(at_bf, qk, vT, ps, pav_t);
    combine_kernel<<<dim3(96), dim3(256), 0, stream>>>(ps, pav_t, av_t);
    q_attn_kernel<<<dim3(49, 96), dim3(256), 0, stream>>>(at_bf, qk, av_t, attn_out);
    gemm_bt_kernel<1><<<dim3(6, 196), dim3(256), 0, stream>>>(attn_out, wpb, qk, nullptr, out, bproj);
}